// Round 5
// baseline (456.571 us; speedup 1.0000x reference)
//
#include <hip/hip_runtime.h>
#include <hip/hip_bf16.h>
#include <math.h>

#define DIN 20
#define C 128
#define HC 256
#define EB1 8192
#define EBS 4096

typedef unsigned short u16;
typedef unsigned int u32;
typedef unsigned long long u64;
typedef __bf16 bf16x8 __attribute__((ext_vector_type(8)));
typedef float f32x4 __attribute__((ext_vector_type(4)));

__device__ __forceinline__ float bfbits2f(unsigned int lo16) {
    return __uint_as_float(lo16 << 16);
}
__device__ __forceinline__ u16 f2bf_rne(float f) {
    unsigned int b = __float_as_uint(f);
    return (u16)((b + 0x7FFFu + ((b >> 16) & 1u)) >> 16);
}

// ---------------- K_init: fused BN stats + per-dst degree count (global atomics) --
// blocks [0,SB): BN stats; blocks [SB,SB+AB): degree count into gcur[key]
__global__ __launch_bounds__(256) void k_init(const float* __restrict__ x, int NR,
    float* __restrict__ stats, int SB,
    const int* __restrict__ dst1, const int* __restrict__ dst2,
    int E1, int L1, int E2, int L2, u32* __restrict__ gcur)
{
    __shared__ float L[256][DIN];
    int t = threadIdx.x;
    if (blockIdx.x < SB) {
        int r = blockIdx.x * 256 + t;
        if (r < NR) {
            #pragma unroll
            for (int k = 0; k < DIN; k++) L[t][k] = x[r * DIN + k];
        } else {
            #pragma unroll
            for (int k = 0; k < DIN; k++) L[t][k] = 0.f;
        }
        __syncthreads();
        if (t < 210) {
            int p = 0, q = t;
            while (q >= DIN - p) { q -= (DIN - p); p++; }
            q += p;
            float acc = 0.f;
            for (int rr = 0; rr < 256; rr++) acc += L[rr][p] * L[rr][q];
            atomicAdd(&stats[p * DIN + q], acc);
            if (p != q) atomicAdd(&stats[q * DIN + p], acc);
        } else if (t < 230) {
            int k = t - 210;
            float acc = 0.f;
            for (int rr = 0; rr < 256; rr++) acc += L[rr][k];
            atomicAdd(&stats[400 + k], acc);
        }
        return;
    }
    int T1 = E1 + L1, T = T1 + E2 + L2;
    int base = (blockIdx.x - SB) * EB1;
    int nE = T - base; if (nE > EB1) nE = EB1;
    for (int j = t; j < nE; j += 256) {
        int i = base + j, key;
        if (i < T1) key = (i < E1) ? dst1[i] : (i - E1);
        else { int k = i - T1; key = NR + ((k < E2) ? dst2[k] : (k - E2)); }
        atomicAdd(&gcur[key], 1u);
    }
}

// ---------------- kScan1: 2048-wide block scan of gcur -> off (local excl) --------
// also zeroes gcur (reused as scatter cursor) and emits per-block totals.
__global__ __launch_bounds__(256) void kScan1(u32* __restrict__ gcur, int n,
    int* __restrict__ off, u32* __restrict__ partial)
{
    __shared__ u32 wsums[4];
    int t = threadIdx.x;
    int base = blockIdx.x * 2048 + t * 8;
    u32 v[8]; u32 s = 0;
    #pragma unroll
    for (int i = 0; i < 8; i++) {
        int gi = base + i;
        v[i] = (gi < n) ? gcur[gi] : 0u;
        s += v[i];
    }
    int l = t & 63, w = t >> 6;
    u32 isc = s;
    #pragma unroll
    for (int o = 1; o < 64; o <<= 1) {
        u32 nn = __shfl_up(isc, o);
        if (l >= o) isc += nn;
    }
    if (l == 63) wsums[w] = isc;
    __syncthreads();
    u32 pre = 0;
    if (w > 0) pre += wsums[0];
    if (w > 1) pre += wsums[1];
    if (w > 2) pre += wsums[2];
    u32 excl = pre + isc - s;
    #pragma unroll
    for (int i = 0; i < 8; i++) {
        int gi = base + i;
        if (gi < n) { off[gi] = (int)excl; gcur[gi] = 0u; excl += v[i]; }
    }
    if (t == 255) partial[blockIdx.x] = pre + isc;
}

// ---------------- K2: precomp (0) + B-pack (1..32) + partial-scan (33) ------------
// stats: [420..547]=BN scale, [548..675]=BN shift, [676..931]=vd1[c*2+h],
//        [932..1187]=vd2[c*2+h'], [1188..1189]=cb[h'],
//        [1200..1455]=u1, [1456..1711]=u2, [1712..2223]=T,
//        [2240..2319]=fv, [2320..2323]=cst
__global__ __launch_bounds__(256) void k_precomp_pack(float* __restrict__ stats,
    const float* __restrict__ W,
    const float* __restrict__ gamma, const float* __restrict__ beta,
    const float* __restrict__ g1_wd, const float* __restrict__ g1_ad,
    const float* __restrict__ g2_wd, const float* __restrict__ g2_ad,
    const float* __restrict__ g1_ws, const float* __restrict__ g1_as,
    const float* __restrict__ g2_ws, const float* __restrict__ g2_as,
    const float* __restrict__ g1b, float invN, u16* __restrict__ wsp,
    const u32* __restrict__ partial, int NPB, u32* __restrict__ pex)
{
    int t = threadIdx.x;
    if (blockIdx.x == 33) {
        __shared__ u32 ps[256];
        ps[t] = (t < NPB) ? partial[t] : 0u;
        __syncthreads();
        if (t == 0) {
            u32 acc = 0;
            for (int i = 0; i < NPB; i++) { u32 c = ps[i]; ps[i] = acc; acc += c; }
        }
        __syncthreads();
        if (t < NPB) pex[t] = ps[t];
        return;
    }
    if (blockIdx.x > 0) {
        int idx0 = ((blockIdx.x - 1) * 256 + t) * 4;
        #pragma unroll
        for (int i = 0; i < 4; i++) {
            int flat = idx0 + i;           // [nt(16)][kb(4)][lane(64)][j(8)]
            int j = flat & 7;
            int lane = (flat >> 3) & 63;
            int kb = (flat >> 9) & 3;
            int nt = flat >> 11;
            int k = kb * 32 + (lane >> 4) * 8 + j;
            int n = nt * 16 + (lane & 15);
            wsp[flat] = f2bf_rne(g2_ws[k * HC + n]);
        }
        return;
    }
    __shared__ float Sm[420];
    __shared__ float Wm[DIN * C];
    __shared__ float vd1s[256];
    __shared__ float vd2s[256];
    __shared__ float sS[128];
    __shared__ float sSh[128];
    for (int i = t; i < 420; i += 256) Sm[i] = stats[i];
    for (int i = t; i < DIN * C; i += 256) Wm[i] = W[i];
    __syncthreads();
    if (t < C) {
        float w[DIN];
        #pragma unroll
        for (int k = 0; k < DIN; k++) w[k] = Wm[k * C + t];
        float mb = 0.f;
        #pragma unroll
        for (int k = 0; k < DIN; k++) mb += Sm[400 + k] * invN * w[k];
        float e2 = 0.f;
        for (int p = 0; p < DIN; p++) {
            float acc2 = 0.f;
            #pragma unroll
            for (int q = 0; q < DIN; q++) acc2 += Sm[p * DIN + q] * w[q];
            e2 += w[p] * acc2;
        }
        e2 *= invN;
        float var = e2 - mb * mb;
        float s = gamma[t] * rsqrtf(var + 1e-5f);
        float sh = beta[t] - s * mb;   // b_rl cancels inside BN
        stats[420 + t] = s;
        stats[548 + t] = sh;
        sS[t] = s;
        sSh[t] = sh;
    }
    {
        int k = t >> 1, h = t & 1;
        const float4* wd1 = (const float4*)(g1_wd + k * HC + h * C);
        const float4* wd2 = (const float4*)(g2_wd + k * HC + h * C);
        const float4* ws1 = (const float4*)(g1_ws + k * HC + h * C);
        const float4* ws2 = (const float4*)(g2_ws + k * HC + h * C);
        const float4* ad1 = (const float4*)(g1_ad + h * C);
        const float4* ad2 = (const float4*)(g2_ad + h * C);
        const float4* as1 = (const float4*)(g1_as + h * C);
        const float4* as2 = (const float4*)(g2_as + h * C);
        float a1 = 0.f, a2 = 0.f, s1 = 0.f, s2 = 0.f;
        #pragma unroll 4
        for (int q = 0; q < 32; q++) {
            float4 x, y;
            x = wd1[q]; y = ad1[q];
            a1 += x.x * y.x + x.y * y.y + x.z * y.z + x.w * y.w;
            x = wd2[q]; y = ad2[q];
            a2 += x.x * y.x + x.y * y.y + x.z * y.z + x.w * y.w;
            x = ws1[q]; y = as1[q];
            s1 += x.x * y.x + x.y * y.y + x.z * y.z + x.w * y.w;
            x = ws2[q]; y = as2[q];
            s2 += x.x * y.x + x.y * y.y + x.z * y.z + x.w * y.w;
        }
        stats[676 + t] = a1;
        stats[932 + t] = a2;
        stats[1200 + t] = s1;
        stats[1456 + t] = s2;
        vd1s[t] = a1;
        vd2s[t] = a2;
    }
    __syncthreads();
    {
        int k = t >> 1, h = t & 1;
        const float4* ws1p = (const float4*)(g1_ws + k * HC + h * C);
        float t0 = 0.f, t1 = 0.f;
        #pragma unroll 4
        for (int q = 0; q < 32; q++) {
            float4 wv = ws1p[q];
            int c = q * 4;
            t0 += wv.x * vd2s[(c + 0) * 2 + 0] + wv.y * vd2s[(c + 1) * 2 + 0]
                + wv.z * vd2s[(c + 2) * 2 + 0] + wv.w * vd2s[(c + 3) * 2 + 0];
            t1 += wv.x * vd2s[(c + 0) * 2 + 1] + wv.y * vd2s[(c + 1) * 2 + 1]
                + wv.z * vd2s[(c + 2) * 2 + 1] + wv.w * vd2s[(c + 3) * 2 + 1];
        }
        stats[1712 + t * 2 + 0] = t0;
        stats[1712 + t * 2 + 1] = t1;
    }
    if (t < 2) {
        float cb = 0.f;
        for (int k = 0; k < C; k++) cb += g1b[k] * vd2s[k * 2 + t];
        stats[1188 + t] = cb;
    }
    if (t < 80) {
        int k = t >> 2, h4 = t & 3, h = h4 & 1;
        const float* vs = (h4 < 2) ? vd1s : vd2s;
        float acc = 0.f;
        for (int c = 0; c < C; c++) acc += sS[c] * Wm[k * C + c] * vs[c * 2 + h];
        stats[2240 + t] = acc;
    } else if (t < 84) {
        int h4 = t - 80, h = h4 & 1;
        const float* vs = (h4 < 2) ? vd1s : vd2s;
        float acc = 0.f;
        for (int c = 0; c < C; c++) acc += sSh[c] * vs[c * 2 + h];
        stats[2320 + h4] = acc;
    }
}

// ---------------- K_feat: r0f GEMV + ing psi + user hs MFMA + edge scatter --------
__global__ __launch_bounds__(256) void k_feat(
    const float* __restrict__ x, int NR, int R0B, int IB, int HB,
    const float* __restrict__ ing_table, const int* __restrict__ ing_ids, int NI,
    const float* __restrict__ user_table, const int* __restrict__ user_ids, int NU,
    const u16* __restrict__ wsp, const float* __restrict__ stats,
    float* __restrict__ a_d, float* __restrict__ advd,
    float* __restrict__ a_si, float* __restrict__ psi,
    u16* __restrict__ hs16, float* __restrict__ a_su,
    const int* __restrict__ src1, const int* __restrict__ dst1,
    const int* __restrict__ src2, const int* __restrict__ dst2,
    int E1, int L1, int E2, int L2,
    const int* __restrict__ off, const u32* __restrict__ pex,
    u32* __restrict__ gcur, int* __restrict__ sorted)
{
    __shared__ float fv[84];
    __shared__ float u1s[256];
    __shared__ float Ts[512];
    __shared__ __align__(16) u16 A[32 * 136];
    __shared__ float u2s[256];
    int t = threadIdx.x;
    int bid = blockIdx.x;
    if (bid < R0B) {
        if (t < 84) fv[t] = stats[2240 + t];
        __syncthreads();
        int r = bid * 256 + t;
        if (r < NR) {
            const float4* xp = (const float4*)(x + (size_t)r * DIN);
            float4 v0 = xp[0], v1 = xp[1], v2 = xp[2], v3 = xp[3], v4 = xp[4];
            float xv[20] = {v0.x, v0.y, v0.z, v0.w, v1.x, v1.y, v1.z, v1.w,
                            v2.x, v2.y, v2.z, v2.w, v3.x, v3.y, v3.z, v3.w,
                            v4.x, v4.y, v4.z, v4.w};
            float a0 = 0.f, a1 = 0.f, b0 = 0.f, b1 = 0.f;
            #pragma unroll
            for (int k = 0; k < DIN; k++) {
                float xvk = xv[k];
                a0 += xvk * fv[k * 4 + 0];
                a1 += xvk * fv[k * 4 + 1];
                b0 += xvk * fv[k * 4 + 2];
                b1 += xvk * fv[k * 4 + 3];
            }
            ((float2*)a_d)[r]  = make_float2(a0 + fv[80], a1 + fv[81]);
            ((float2*)advd)[r] = make_float2(b0 + fv[82], b1 + fv[83]);
        }
        return;
    }
    if (bid < R0B + IB) {
        u1s[t] = stats[1200 + t];
        Ts[t] = stats[1712 + t];
        Ts[256 + t] = stats[1968 + t];
        __syncthreads();
        int r = t >> 3, cg = t & 7;
        int row = (bid - R0B) * 32 + r;
        float as0 = 0.f, as1 = 0.f, p00 = 0.f, p01 = 0.f, p10 = 0.f, p11 = 0.f;
        if (row < NI) {
            const float* xp = ing_table + (size_t)ing_ids[row] * C + cg * 16;
            #pragma unroll
            for (int q = 0; q < 4; q++) {
                float4 v = ((const float4*)xp)[q];
                float xvv[4] = {v.x, v.y, v.z, v.w};
                #pragma unroll
                for (int jj = 0; jj < 4; jj++) {
                    int k = cg * 16 + q * 4 + jj;
                    float xx = xvv[jj];
                    as0 += xx * u1s[k * 2 + 0];
                    as1 += xx * u1s[k * 2 + 1];
                    p00 += xx * Ts[k * 4 + 0];
                    p01 += xx * Ts[k * 4 + 1];
                    p10 += xx * Ts[k * 4 + 2];
                    p11 += xx * Ts[k * 4 + 3];
                }
            }
        }
        #pragma unroll
        for (int m = 1; m <= 4; m <<= 1) {
            as0 += __shfl_xor(as0, m); as1 += __shfl_xor(as1, m);
            p00 += __shfl_xor(p00, m); p01 += __shfl_xor(p01, m);
            p10 += __shfl_xor(p10, m); p11 += __shfl_xor(p11, m);
        }
        if (cg == 0 && row < NI) {
            ((float2*)a_si)[row] = make_float2(as0, as1);
            float4 pv; pv.x = p00; pv.y = p01; pv.z = p10; pv.w = p11;
            ((float4*)psi)[row] = pv;
        }
        return;
    }
    if (bid < R0B + IB + HB) {
        u2s[t] = stats[1456 + t];
        int rowBase = (bid - R0B - IB) * 32;
        int r = t >> 3, cg = t & 7;
        int row = rowBase + r;
        float xv[16];
        if (row < NU) {
            const float* xp = user_table + (size_t)user_ids[row] * C + cg * 16;
            #pragma unroll
            for (int q = 0; q < 4; q++) {
                float4 v = ((const float4*)xp)[q];
                xv[q * 4 + 0] = v.x; xv[q * 4 + 1] = v.y;
                xv[q * 4 + 2] = v.z; xv[q * 4 + 3] = v.w;
            }
        } else {
            #pragma unroll
            for (int q = 0; q < 16; q++) xv[q] = 0.f;
        }
        float ss = 0.f;
        #pragma unroll
        for (int q = 0; q < 16; q++) ss += xv[q] * xv[q];
        #pragma unroll
        for (int m = 1; m <= 4; m <<= 1) ss += __shfl_xor(ss, m);
        float nn = sqrtf(ss);
        float f = (nn > 1.f) ? 1.f / (nn + 1e-7f) : 1.f;
        float as0 = 0.f, as1 = 0.f;
        #pragma unroll
        for (int q = 0; q < 16; q++) {
            xv[q] *= f;
            int k = cg * 16 + q;
            as0 += xv[q] * u2s[k * 2 + 0];
            as1 += xv[q] * u2s[k * 2 + 1];
        }
        #pragma unroll
        for (int m = 1; m <= 4; m <<= 1) {
            as0 += __shfl_xor(as0, m); as1 += __shfl_xor(as1, m);
        }
        if (cg == 0 && row < NU) ((float2*)a_su)[row] = make_float2(as0, as1);
        {
            union { u16 h[16]; uint4 u4[2]; } pk;
            #pragma unroll
            for (int q = 0; q < 16; q++) pk.h[q] = f2bf_rne(xv[q]);
            uint4* dst = (uint4*)&A[r * 136 + cg * 16];
            dst[0] = pk.u4[0];
            dst[1] = pk.u4[1];
        }
        __syncthreads();
        int w = t >> 6, l = t & 63;
        int m15 = l & 15, q4 = l >> 4;
        bf16x8 afrag[2][4];
        #pragma unroll
        for (int mt = 0; mt < 2; mt++)
            #pragma unroll
            for (int kb = 0; kb < 4; kb++)
                afrag[mt][kb] = *(const bf16x8*)&A[(mt * 16 + m15) * 136 + kb * 32 + q4 * 8];
        f32x4 acc[2][4];
        #pragma unroll
        for (int mt = 0; mt < 2; mt++)
            #pragma unroll
            for (int i = 0; i < 4; i++) acc[mt][i] = (f32x4){0.f, 0.f, 0.f, 0.f};
        #pragma unroll
        for (int kb = 0; kb < 4; kb++) {
            #pragma unroll
            for (int i = 0; i < 4; i++) {
                int nt = w * 4 + i;
                bf16x8 bfrag = *(const bf16x8*)&wsp[((nt * 4 + kb) * 64 + l) * 8];
                acc[0][i] = __builtin_amdgcn_mfma_f32_16x16x32_bf16(afrag[0][kb], bfrag, acc[0][i], 0, 0, 0);
                acc[1][i] = __builtin_amdgcn_mfma_f32_16x16x32_bf16(afrag[1][kb], bfrag, acc[1][i], 0, 0, 0);
            }
        }
        #pragma unroll
        for (int mt = 0; mt < 2; mt++) {
            #pragma unroll
            for (int i = 0; i < 4; i++) {
                int col = (w * 4 + i) * 16 + m15;
                #pragma unroll
                for (int rr = 0; rr < 4; rr++) {
                    int rw = rowBase + mt * 16 + q4 * 4 + rr;
                    if (rw < NU) hs16[(size_t)rw * HC + col] = f2bf_rne(acc[mt][i][rr]);
                }
            }
        }
        return;
    }
    // ---- scatter role: sorted[off[key]+pex+cursor] = src ----
    int sb = bid - R0B - IB - HB;
    int T1 = E1 + L1, T = T1 + E2 + L2;
    int base = sb * EBS;
    int nE = T - base; if (nE > EBS) nE = EBS;
    for (int j = t; j < nE; j += 256) {
        int i = base + j, s, key;
        if (i < T1) {
            if (i < E1) { s = src1[i]; key = dst1[i]; }
            else        { s = i - E1; key = i - E1; }
        } else {
            int k = i - T1;
            if (k < E2) { s = src2[k]; key = NR + dst2[k]; }
            else        { s = k - E2; key = NR + (k - E2); }
        }
        u32 pos = (u32)off[key] + pex[key >> 11] + atomicAdd(&gcur[key], 1u);
        sorted[pos] = s;
    }
}

// ---------------- Fused aggregation: GAT1 (psi) then GAT2 (hs16 gather) -----------
// Phase 2: 32 lanes x 16B cover one 512B row -> 2 edges per wave-step.
__global__ __launch_bounds__(256) void k_agg(const int* __restrict__ off,
    const u32* __restrict__ pex, const int* __restrict__ sorted,
    const float* __restrict__ a_si, const float* __restrict__ psi,
    const float* __restrict__ a_d1, const float* __restrict__ advd,
    const float* __restrict__ cb,
    const float* __restrict__ a_su, const u16* __restrict__ hs16,
    const float* __restrict__ bias, int NR, float* __restrict__ out)
{
    int wave = threadIdx.x >> 6, lane = threadIdx.x & 63;
    int d = blockIdx.x * 4 + wave;
    if (d >= NR) return;
    // ---------- phase 1: GAT1 psi aggregation ----------
    int beg = off[d] + (int)pex[d >> 11];
    int end = off[d + 1] + (int)pex[(d + 1) >> 11];
    float ad0 = a_d1[d * 2 + 0], ad1 = a_d1[d * 2 + 1];
    float w0s = 0.f, w1s = 0.f, a00 = 0.f, a01 = 0.f, a10 = 0.f, a11 = 0.f;
    for (int j = beg + lane; j < end; j += 64) {
        int s = sorted[j];
        float2 as = ((const float2*)a_si)[s];
        float e0 = as.x + ad0; e0 = (e0 >= 0.f) ? e0 : 0.2f * e0;
        float e1 = as.y + ad1; e1 = (e1 >= 0.f) ? e1 : 0.2f * e1;
        float x0 = __expf(e0), x1 = __expf(e1);
        float4 p = ((const float4*)psi)[s];
        w0s += x0; w1s += x1;
        a00 += x0 * p.x; a01 += x0 * p.y;
        a10 += x1 * p.z; a11 += x1 * p.w;
    }
    #pragma unroll
    for (int o = 1; o < 64; o <<= 1) {
        w0s += __shfl_xor(w0s, o); w1s += __shfl_xor(w1s, o);
        a00 += __shfl_xor(a00, o); a01 += __shfl_xor(a01, o);
        a10 += __shfl_xor(a10, o); a11 += __shfl_xor(a11, o);
    }
    float inv0g = 1.f / (w0s + 1e-16f), inv1g = 1.f / (w1s + 1e-16f);
    float r0 = advd[d * 2 + 0] + cb[0] + 0.5f * (a00 * inv0g + a10 * inv1g);
    float r1 = advd[d * 2 + 1] + cb[1] + 0.5f * (a01 * inv0g + a11 * inv1g);
    // ---------- phase 2: GAT2 hs16 row gather (2 edges per step) ----------
    int i2 = NR + d;
    int beg2 = off[i2] + (int)pex[i2 >> 11];
    int end2 = off[i2 + 1] + (int)pex[(i2 + 1) >> 11];
    int g = lane >> 5;                 // edge-parity group (0: even, 1: odd)
    int lg = lane & 31;
    int head = lg >> 4;                // head this lane accumulates
    int hq = lg & 15;                  // 8-channel group within head
    u32 laneoff = (u32)(head * 256 + hq * 16);
    int hsel = head << 5;              // weight source half
    float adh = (lane >= 32) ? r1 : r0;   // batch-phase head = lane>>5
    float wsum = 0.f;
    float acc[8];
    #pragma unroll
    for (int k = 0; k < 8; k++) acc[k] = 0.f;
    const char* hbase = (const char*)hs16;

    for (int base = beg2; base < end2; base += 32) {
        int rem = end2 - base; if (rem > 32) rem = 32;
        int j = lg; if (j >= rem) j = rem - 1;
        int sp = sorted[base + j];
        u32 boff = ((u32)sp) << 9;     // row byte offset (*HC*2)
        float asv = a_su[sp * 2 + g];  // lanes<32: head0 logit; >=32: head1
        float ee = asv + adh; ee = (ee >= 0.f) ? ee : 0.2f * ee;
        float wcomb = __expf(ee);      // weight(edge lg, head lane>>5)
        for (int e = 0; e < rem; e += 2) {
            int eg = e + g;
            bool valid = eg < rem;
            int srcl = valid ? eg : rem - 1;
            u32 bo = __shfl(boff, srcl);
            float W = __shfl(wcomb, hsel + srcl);
            W = valid ? W : 0.f;
            uint4 gg = *(const uint4*)(hbase + (bo + laneoff));
            wsum += W;
            acc[0] += W * bfbits2f(gg.x & 0xFFFFu);
            acc[1] += W * __uint_as_float(gg.x & 0xFFFF0000u);
            acc[2] += W * bfbits2f(gg.y & 0xFFFFu);
            acc[3] += W * __uint_as_float(gg.y & 0xFFFF0000u);
            acc[4] += W * bfbits2f(gg.z & 0xFFFFu);
            acc[5] += W * __uint_as_float(gg.z & 0xFFFF0000u);
            acc[6] += W * bfbits2f(gg.w & 0xFFFFu);
            acc[7] += W * __uint_as_float(gg.w & 0xFFFF0000u);
        }
    }
    // merge edge-parity groups (lane^32: same head/channels, other edge subset)
    wsum += __shfl_xor(wsum, 32);
    #pragma unroll
    for (int k = 0; k < 8; k++) acc[k] += __shfl_xor(acc[k], 32);
    float inv = 1.f / (wsum + 1e-16f);
    #pragma unroll
    for (int k = 0; k < 8; k++) acc[k] *= inv;
    // head mean: lane^16 holds the other head, same channels
    #pragma unroll
    for (int k = 0; k < 8; k++) acc[k] = 0.5f * (acc[k] + __shfl_xor(acc[k], 16));
    if (lane < 16) {
        const float4* b4 = (const float4*)bias;
        float4 bb0 = b4[hq * 2], bb1 = b4[hq * 2 + 1];
        float4 o0, o1;
        o0.x = acc[0] + bb0.x; o0.y = acc[1] + bb0.y;
        o0.z = acc[2] + bb0.z; o0.w = acc[3] + bb0.w;
        o1.x = acc[4] + bb1.x; o1.y = acc[5] + bb1.y;
        o1.z = acc[6] + bb1.z; o1.w = acc[7] + bb1.w;
        float4* op = (float4*)(out + (size_t)d * C + hq * 8);
        op[0] = o0; op[1] = o1;
    }
}

extern "C" void kernel_launch(void* const* d_in, const int* in_sizes, int n_in,
                              void* d_out, int out_size, void* d_ws, size_t ws_size,
                              hipStream_t stream) {
    const int*   user_ids       = (const int*)d_in[0];
    const int*   ingredient_ids = (const int*)d_in[1];
    const float* recipe_x       = (const float*)d_in[2];
    const int*   ing_src        = (const int*)d_in[3];
    const int*   ing_dst        = (const int*)d_in[4];
    const int*   ub_src         = (const int*)d_in[5];
    const int*   ub_dst         = (const int*)d_in[6];
    const float* user_table     = (const float*)d_in[7];
    const float* ing_table      = (const float*)d_in[8];
    const float* W_rl           = (const float*)d_in[9];
    const float* bn_gamma       = (const float*)d_in[11];
    const float* bn_beta        = (const float*)d_in[12];
    const float* g1_ws          = (const float*)d_in[13];
    const float* g1_wd          = (const float*)d_in[14];
    const float* g1_as          = (const float*)d_in[15];
    const float* g1_ad          = (const float*)d_in[16];
    const float* g1_b           = (const float*)d_in[17];
    const float* g2_ws          = (const float*)d_in[18];
    const float* g2_wd          = (const float*)d_in[19];
    const float* g2_as          = (const float*)d_in[20];
    const float* g2_ad          = (const float*)d_in[21];
    const float* g2_b           = (const float*)d_in[22];

    int NU = in_sizes[0];
    int NI = in_sizes[1];
    int NR = in_sizes[2] / DIN;
    int E1 = in_sizes[3];
    int E2 = in_sizes[5];
    int Nmax = (NI > NU) ? NI : NU;
    int L1 = (NI < NR) ? NI : NR;
    int L2 = (NU < NR) ? NU : NR;
    int Etot = E1 + L1 + E2 + L2;
    int n2 = 2 * NR;
    int NPB = (n2 + 1 + 2047) >> 11;   // scan blocks over n2+1 counters

    char* w = (char*)d_ws;
    u16*   hs16  = (u16*)w;    w += (size_t)Nmax * HC * 2;
    float* a_si  = (float*)w;  w += (size_t)NI * 2 * 4;
    float* a_su  = (float*)w;  w += (size_t)NU * 2 * 4;
    float* psi   = (float*)w;  w += (size_t)NI * 4 * 4;
    float* a_d   = (float*)w;  w += (size_t)NR * 2 * 4;
    float* advd  = (float*)w;  w += (size_t)NR * 2 * 4;
    float* stats = (float*)w;  w += 2432 * 4;
    u32*   gcur  = (u32*)w;    w += (size_t)(n2 + 1) * 4;   // adjacent: one memset
    u16*   wsp   = (u16*)w;    w += 32768 * 2;
    int*   off   = (int*)w;    w += (size_t)(n2 + 1) * 4;
    u32*   partial = (u32*)w;  w += 256 * 4;
    u32*   pex   = (u32*)w;    w += 256 * 4;
    int*   sorted= (int*)w;    w += (size_t)Etot * 4;

    // zero stats[0..420) + degree counters in one shot
    hipMemsetAsync(stats, 0, (size_t)(2432 + n2 + 1) * 4, stream);

    int SB = (NR + 255) / 256;
    int AB = (Etot + EB1 - 1) / EB1;
    k_init<<<SB + AB, 256, 0, stream>>>(recipe_x, NR, stats, SB,
                                        ing_dst, ub_dst, E1, L1, E2, L2, gcur);
    kScan1<<<NPB, 256, 0, stream>>>(gcur, n2 + 1, off, partial);
    k_precomp_pack<<<34, 256, 0, stream>>>(stats, W_rl, bn_gamma, bn_beta,
                                           g1_wd, g1_ad, g2_wd, g2_ad,
                                           g1_ws, g1_as, g2_ws, g2_as, g1_b,
                                           1.0f / NR, wsp, partial, NPB, pex);
    int R0B = (NR + 255) / 256;
    int IB  = (NI + 31) / 32;
    int HB  = (NU + 31) / 32;
    int SCB = (Etot + EBS - 1) / EBS;
    k_feat<<<R0B + IB + HB + SCB, 256, 0, stream>>>(recipe_x, NR, R0B, IB, HB,
                                              ing_table, ingredient_ids, NI,
                                              user_table, user_ids, NU,
                                              wsp, stats, a_d, advd, a_si, psi,
                                              hs16, a_su,
                                              ing_src, ing_dst, ub_src, ub_dst,
                                              E1, L1, E2, L2, off, pex, gcur, sorted);
    k_agg<<<(NR + 3) / 4, 256, 0, stream>>>(off, pex, sorted, a_si, psi, a_d, advd,
                                            stats + 1188, a_su, hs16, g2_b, NR,
                                            (float*)d_out);
}

// Round 6
// 358.767 us; speedup vs baseline: 1.2726x; 1.2726x over previous
//
#include <hip/hip_runtime.h>
#include <hip/hip_bf16.h>
#include <math.h>

#define DIN 20
#define C 128
#define HC 256
#define EB1 8192
#define EB2 2048
#define MAXNB 400

typedef unsigned short u16;
typedef unsigned int u32;
typedef unsigned long long u64;
typedef __bf16 bf16x8 __attribute__((ext_vector_type(8)));
typedef float f32x4 __attribute__((ext_vector_type(4)));

__device__ __forceinline__ float bfbits2f(unsigned int lo16) {
    return __uint_as_float(lo16 << 16);
}
__device__ __forceinline__ u16 f2bf_rne(float f) {
    unsigned int b = __float_as_uint(f);
    return (u16)((b + 0x7FFFu + ((b >> 16) & 1u)) >> 16);
}

// exclusive scan of cnt[0..511] -> off[0..511]; wave-shuffle scan, 2 barriers total
__device__ __forceinline__ void scan512f(u32* cnt, u32* off, u32* wsum4) {
    int t = threadIdx.x;
    int l = t & 63, w = t >> 6;
    u32 a = cnt[2 * t], b = cnt[2 * t + 1];
    u32 s = a + b;
    u32 isc = s;
    #pragma unroll
    for (int o = 1; o < 64; o <<= 1) {
        u32 n = __shfl_up(isc, o);
        if (l >= o) isc += n;
    }
    if (l == 63) wsum4[w] = isc;
    __syncthreads();
    u32 pre = 0;
    if (w > 0) pre += wsum4[0];
    if (w > 1) pre += wsum4[1];
    if (w > 2) pre += wsum4[2];
    u32 excl = pre + isc - s;
    off[2 * t] = excl;
    off[2 * t + 1] = excl + a;
    __syncthreads();
}

__device__ __forceinline__ void edge_at(int i, const int* s1, const int* d1,
    const int* s2, const int* d2, int E1, int T1, int E2, int NR,
    int& s, int& key)
{
    if (i < T1) {
        if (i < E1) { s = s1[i]; key = d1[i]; }
        else        { s = i - E1; key = i - E1; }
    } else {
        int k = i - T1;
        if (k < E2) { s = s2[k]; key = NR + d2[k]; }
        else        { s = k - E2; key = NR + (k - E2); }
    }
}

// ---------------- K_init: fused BN stats + bucket histogram -----------------------
__global__ __launch_bounds__(256) void k_init(const float* __restrict__ x, int NR,
    float* __restrict__ stats, int SB,
    const int* __restrict__ src1, const int* __restrict__ dst1,
    const int* __restrict__ src2, const int* __restrict__ dst2,
    int E1, int L1, int E2, int L2, int NB, u32* __restrict__ bucketCnt)
{
    __shared__ float L[256][DIN];
    __shared__ u32 cnt[MAXNB];
    int t = threadIdx.x;
    if (blockIdx.x < SB) {
        int r = blockIdx.x * 256 + t;
        if (r < NR) {
            #pragma unroll
            for (int k = 0; k < DIN; k++) L[t][k] = x[r * DIN + k];
        } else {
            #pragma unroll
            for (int k = 0; k < DIN; k++) L[t][k] = 0.f;
        }
        __syncthreads();
        if (t < 210) {
            int p = 0, q = t;
            while (q >= DIN - p) { q -= (DIN - p); p++; }
            q += p;
            float acc = 0.f;
            for (int rr = 0; rr < 256; rr++) acc += L[rr][p] * L[rr][q];
            atomicAdd(&stats[p * DIN + q], acc);
            if (p != q) atomicAdd(&stats[q * DIN + p], acc);
        } else if (t < 230) {
            int k = t - 210;
            float acc = 0.f;
            for (int rr = 0; rr < 256; rr++) acc += L[rr][k];
            atomicAdd(&stats[400 + k], acc);
        }
        return;
    }
    for (int i = t; i < NB; i += 256) cnt[i] = 0;
    __syncthreads();
    int T1 = E1 + L1, T = T1 + E2 + L2;
    int base = (blockIdx.x - SB) * EB1;
    int nE = T - base; if (nE > EB1) nE = EB1;
    for (int j = t; j < nE; j += 256) {
        int s, key;
        edge_at(base + j, src1, dst1, src2, dst2, E1, T1, E2, NR, s, key);
        atomicAdd(&cnt[key >> 9], 1u);
    }
    __syncthreads();
    for (int b = t; b < NB; b += 256) {
        u32 c = cnt[b];
        if (c) atomicAdd(&bucketCnt[b], c);
    }
}

// ---------------- K2: precomp (0) + B-pack (1..32) + bucket scan (33) -------------
__global__ __launch_bounds__(256) void k_precomp_pack(float* __restrict__ stats,
    const float* __restrict__ W,
    const float* __restrict__ gamma, const float* __restrict__ beta,
    const float* __restrict__ g1_wd, const float* __restrict__ g1_ad,
    const float* __restrict__ g2_wd, const float* __restrict__ g2_ad,
    const float* __restrict__ g1_ws, const float* __restrict__ g1_as,
    const float* __restrict__ g2_ws, const float* __restrict__ g2_as,
    const float* __restrict__ g1b, float invN, u16* __restrict__ wsp,
    const u32* __restrict__ bucketCnt, int NB, int n2,
    u32* __restrict__ bucketBase, u32* __restrict__ gcur, int* __restrict__ off)
{
    int t = threadIdx.x;
    if (blockIdx.x == 33) {
        __shared__ u32 cnt[512], offL[512], wsum4[4];
        for (int i = t; i < 512; i += 256) cnt[i] = (i < NB) ? bucketCnt[i] : 0u;
        __syncthreads();
        scan512f(cnt, offL, wsum4);
        for (int i = t; i < NB; i += 256) {
            u32 v = offL[i];
            bucketBase[i] = v;
            gcur[i] = v;
        }
        if (t == 0) {
            u32 total = offL[511] + cnt[511];
            bucketBase[NB] = total;
            off[n2] = (int)total;
        }
        return;
    }
    if (blockIdx.x > 0) {
        int idx0 = ((blockIdx.x - 1) * 256 + t) * 4;
        #pragma unroll
        for (int i = 0; i < 4; i++) {
            int flat = idx0 + i;           // [nt(16)][kb(4)][lane(64)][j(8)]
            int j = flat & 7;
            int lane = (flat >> 3) & 63;
            int kb = (flat >> 9) & 3;
            int nt = flat >> 11;
            int k = kb * 32 + (lane >> 4) * 8 + j;
            int n = nt * 16 + (lane & 15);
            wsp[flat] = f2bf_rne(g2_ws[k * HC + n]);
        }
        return;
    }
    __shared__ float Sm[420];
    __shared__ float Wm[DIN * C];
    __shared__ float vd1s[256];
    __shared__ float vd2s[256];
    __shared__ float sS[128];
    __shared__ float sSh[128];
    for (int i = t; i < 420; i += 256) Sm[i] = stats[i];
    for (int i = t; i < DIN * C; i += 256) Wm[i] = W[i];
    __syncthreads();
    if (t < C) {
        float w[DIN];
        #pragma unroll
        for (int k = 0; k < DIN; k++) w[k] = Wm[k * C + t];
        float mb = 0.f;
        #pragma unroll
        for (int k = 0; k < DIN; k++) mb += Sm[400 + k] * invN * w[k];
        float e2 = 0.f;
        for (int p = 0; p < DIN; p++) {
            float acc2 = 0.f;
            #pragma unroll
            for (int q = 0; q < DIN; q++) acc2 += Sm[p * DIN + q] * w[q];
            e2 += w[p] * acc2;
        }
        e2 *= invN;
        float var = e2 - mb * mb;
        float s = gamma[t] * rsqrtf(var + 1e-5f);
        float sh = beta[t] - s * mb;   // b_rl cancels inside BN
        stats[420 + t] = s;
        stats[548 + t] = sh;
        sS[t] = s;
        sSh[t] = sh;
    }
    {
        int k = t >> 1, h = t & 1;
        const float4* wd1 = (const float4*)(g1_wd + k * HC + h * C);
        const float4* wd2 = (const float4*)(g2_wd + k * HC + h * C);
        const float4* ws1 = (const float4*)(g1_ws + k * HC + h * C);
        const float4* ws2 = (const float4*)(g2_ws + k * HC + h * C);
        const float4* ad1 = (const float4*)(g1_ad + h * C);
        const float4* ad2 = (const float4*)(g2_ad + h * C);
        const float4* as1 = (const float4*)(g1_as + h * C);
        const float4* as2 = (const float4*)(g2_as + h * C);
        float a1 = 0.f, a2 = 0.f, s1 = 0.f, s2 = 0.f;
        #pragma unroll 4
        for (int q = 0; q < 32; q++) {
            float4 x, y;
            x = wd1[q]; y = ad1[q];
            a1 += x.x * y.x + x.y * y.y + x.z * y.z + x.w * y.w;
            x = wd2[q]; y = ad2[q];
            a2 += x.x * y.x + x.y * y.y + x.z * y.z + x.w * y.w;
            x = ws1[q]; y = as1[q];
            s1 += x.x * y.x + x.y * y.y + x.z * y.z + x.w * y.w;
            x = ws2[q]; y = as2[q];
            s2 += x.x * y.x + x.y * y.y + x.z * y.z + x.w * y.w;
        }
        stats[676 + t] = a1;
        stats[932 + t] = a2;
        stats[1200 + t] = s1;
        stats[1456 + t] = s2;
        vd1s[t] = a1;
        vd2s[t] = a2;
    }
    __syncthreads();
    {
        int k = t >> 1, h = t & 1;
        const float4* ws1p = (const float4*)(g1_ws + k * HC + h * C);
        float t0 = 0.f, t1 = 0.f;
        #pragma unroll 4
        for (int q = 0; q < 32; q++) {
            float4 wv = ws1p[q];
            int c = q * 4;
            t0 += wv.x * vd2s[(c + 0) * 2 + 0] + wv.y * vd2s[(c + 1) * 2 + 0]
                + wv.z * vd2s[(c + 2) * 2 + 0] + wv.w * vd2s[(c + 3) * 2 + 0];
            t1 += wv.x * vd2s[(c + 0) * 2 + 1] + wv.y * vd2s[(c + 1) * 2 + 1]
                + wv.z * vd2s[(c + 2) * 2 + 1] + wv.w * vd2s[(c + 3) * 2 + 1];
        }
        stats[1712 + t * 2 + 0] = t0;
        stats[1712 + t * 2 + 1] = t1;
    }
    if (t < 2) {
        float cb = 0.f;
        for (int k = 0; k < C; k++) cb += g1b[k] * vd2s[k * 2 + t];
        stats[1188 + t] = cb;
    }
    if (t < 80) {
        int k = t >> 2, h4 = t & 3, h = h4 & 1;
        const float* vs = (h4 < 2) ? vd1s : vd2s;
        float acc = 0.f;
        for (int c = 0; c < C; c++) acc += sS[c] * Wm[k * C + c] * vs[c * 2 + h];
        stats[2240 + t] = acc;
    } else if (t < 84) {
        int h4 = t - 80, h = h4 & 1;
        const float* vs = (h4 < 2) ? vd1s : vd2s;
        float acc = 0.f;
        for (int c = 0; c < C; c++) acc += sSh[c] * vs[c * 2 + h];
        stats[2320 + h4] = acc;
    }
}

// ---------------- K_feat: fused r0f GEMV + ingredient psi + user hs MFMA ----------
__global__ __launch_bounds__(256) void k_feat(
    const float* __restrict__ x, int NR, int R0B, int IB,
    const float* __restrict__ ing_table, const int* __restrict__ ing_ids, int NI,
    const float* __restrict__ user_table, const int* __restrict__ user_ids, int NU,
    const u16* __restrict__ wsp, const float* __restrict__ stats,
    float* __restrict__ a_d, float* __restrict__ advd,
    float* __restrict__ a_si, float* __restrict__ psi,
    u16* __restrict__ hs16, float* __restrict__ a_su)
{
    __shared__ float fv[84];
    __shared__ float u1s[256];
    __shared__ float Ts[512];
    __shared__ __align__(16) u16 A[32 * 136];
    __shared__ float u2s[256];
    int t = threadIdx.x;
    int bid = blockIdx.x;
    if (bid < R0B) {
        if (t < 84) fv[t] = stats[2240 + t];
        __syncthreads();
        int r = bid * 256 + t;
        if (r < NR) {
            const float4* xp = (const float4*)(x + (size_t)r * DIN);
            float4 v0 = xp[0], v1 = xp[1], v2 = xp[2], v3 = xp[3], v4 = xp[4];
            float xv[20] = {v0.x, v0.y, v0.z, v0.w, v1.x, v1.y, v1.z, v1.w,
                            v2.x, v2.y, v2.z, v2.w, v3.x, v3.y, v3.z, v3.w,
                            v4.x, v4.y, v4.z, v4.w};
            float a0 = 0.f, a1 = 0.f, b0 = 0.f, b1 = 0.f;
            #pragma unroll
            for (int k = 0; k < DIN; k++) {
                float xvk = xv[k];
                a0 += xvk * fv[k * 4 + 0];
                a1 += xvk * fv[k * 4 + 1];
                b0 += xvk * fv[k * 4 + 2];
                b1 += xvk * fv[k * 4 + 3];
            }
            ((float2*)a_d)[r]  = make_float2(a0 + fv[80], a1 + fv[81]);
            ((float2*)advd)[r] = make_float2(b0 + fv[82], b1 + fv[83]);
        }
        return;
    }
    if (bid < R0B + IB) {
        u1s[t] = stats[1200 + t];
        Ts[t] = stats[1712 + t];
        Ts[256 + t] = stats[1968 + t];
        __syncthreads();
        int r = t >> 3, cg = t & 7;
        int row = (bid - R0B) * 32 + r;
        float as0 = 0.f, as1 = 0.f, p00 = 0.f, p01 = 0.f, p10 = 0.f, p11 = 0.f;
        if (row < NI) {
            const float* xp = ing_table + (size_t)ing_ids[row] * C + cg * 16;
            #pragma unroll
            for (int q = 0; q < 4; q++) {
                float4 v = ((const float4*)xp)[q];
                float xvv[4] = {v.x, v.y, v.z, v.w};
                #pragma unroll
                for (int jj = 0; jj < 4; jj++) {
                    int k = cg * 16 + q * 4 + jj;
                    float xx = xvv[jj];
                    as0 += xx * u1s[k * 2 + 0];
                    as1 += xx * u1s[k * 2 + 1];
                    p00 += xx * Ts[k * 4 + 0];
                    p01 += xx * Ts[k * 4 + 1];
                    p10 += xx * Ts[k * 4 + 2];
                    p11 += xx * Ts[k * 4 + 3];
                }
            }
        }
        #pragma unroll
        for (int m = 1; m <= 4; m <<= 1) {
            as0 += __shfl_xor(as0, m); as1 += __shfl_xor(as1, m);
            p00 += __shfl_xor(p00, m); p01 += __shfl_xor(p01, m);
            p10 += __shfl_xor(p10, m); p11 += __shfl_xor(p11, m);
        }
        if (cg == 0 && row < NI) {
            ((float2*)a_si)[row] = make_float2(as0, as1);
            float4 pv; pv.x = p00; pv.y = p01; pv.z = p10; pv.w = p11;
            ((float4*)psi)[row] = pv;
        }
        return;
    }
    u2s[t] = stats[1456 + t];
    int rowBase = (bid - R0B - IB) * 32;
    int r = t >> 3, cg = t & 7;
    int row = rowBase + r;
    float xv[16];
    if (row < NU) {
        const float* xp = user_table + (size_t)user_ids[row] * C + cg * 16;
        #pragma unroll
        for (int q = 0; q < 4; q++) {
            float4 v = ((const float4*)xp)[q];
            xv[q * 4 + 0] = v.x; xv[q * 4 + 1] = v.y;
            xv[q * 4 + 2] = v.z; xv[q * 4 + 3] = v.w;
        }
    } else {
        #pragma unroll
        for (int q = 0; q < 16; q++) xv[q] = 0.f;
    }
    float ss = 0.f;
    #pragma unroll
    for (int q = 0; q < 16; q++) ss += xv[q] * xv[q];
    #pragma unroll
    for (int m = 1; m <= 4; m <<= 1) ss += __shfl_xor(ss, m);
    float nn = sqrtf(ss);
    float f = (nn > 1.f) ? 1.f / (nn + 1e-7f) : 1.f;
    float as0 = 0.f, as1 = 0.f;
    #pragma unroll
    for (int q = 0; q < 16; q++) {
        xv[q] *= f;
        int k = cg * 16 + q;
        as0 += xv[q] * u2s[k * 2 + 0];
        as1 += xv[q] * u2s[k * 2 + 1];
    }
    #pragma unroll
    for (int m = 1; m <= 4; m <<= 1) {
        as0 += __shfl_xor(as0, m); as1 += __shfl_xor(as1, m);
    }
    if (cg == 0 && row < NU) ((float2*)a_su)[row] = make_float2(as0, as1);
    {
        union { u16 h[16]; uint4 u4[2]; } pk;
        #pragma unroll
        for (int q = 0; q < 16; q++) pk.h[q] = f2bf_rne(xv[q]);
        uint4* dst = (uint4*)&A[r * 136 + cg * 16];
        dst[0] = pk.u4[0];
        dst[1] = pk.u4[1];
    }
    __syncthreads();
    int w = t >> 6, l = t & 63;
    int m15 = l & 15, q4 = l >> 4;
    bf16x8 afrag[2][4];
    #pragma unroll
    for (int mt = 0; mt < 2; mt++)
        #pragma unroll
        for (int kb = 0; kb < 4; kb++)
            afrag[mt][kb] = *(const bf16x8*)&A[(mt * 16 + m15) * 136 + kb * 32 + q4 * 8];
    f32x4 acc[2][4];
    #pragma unroll
    for (int mt = 0; mt < 2; mt++)
        #pragma unroll
        for (int i = 0; i < 4; i++) acc[mt][i] = (f32x4){0.f, 0.f, 0.f, 0.f};
    #pragma unroll
    for (int kb = 0; kb < 4; kb++) {
        #pragma unroll
        for (int i = 0; i < 4; i++) {
            int nt = w * 4 + i;
            bf16x8 bfrag = *(const bf16x8*)&wsp[((nt * 4 + kb) * 64 + l) * 8];
            acc[0][i] = __builtin_amdgcn_mfma_f32_16x16x32_bf16(afrag[0][kb], bfrag, acc[0][i], 0, 0, 0);
            acc[1][i] = __builtin_amdgcn_mfma_f32_16x16x32_bf16(afrag[1][kb], bfrag, acc[1][i], 0, 0, 0);
        }
    }
    #pragma unroll
    for (int mt = 0; mt < 2; mt++) {
        #pragma unroll
        for (int i = 0; i < 4; i++) {
            int col = (w * 4 + i) * 16 + m15;
            #pragma unroll
            for (int rr = 0; rr < 4; rr++) {
                int rw = rowBase + mt * 16 + q4 * 4 + rr;
                if (rw < NU) hs16[(size_t)rw * HC + col] = f2bf_rne(acc[mt][i][rr]);
            }
        }
    }
}

// A2: local counting sort by bucket; EB2=2048 -> ~40KB LDS, good occupancy
__global__ __launch_bounds__(256) void kA2(const int* __restrict__ src1, const int* __restrict__ dst1,
    const int* __restrict__ src2, const int* __restrict__ dst2,
    int E1, int L1, int E2, int L2, int NR, int NB,
    u32* __restrict__ gcur, u64* __restrict__ pairs)
{
    __shared__ u64 ldsE[EB2];
    __shared__ u64 ldsS[EB2];
    __shared__ u32 cntA[512], cntB[512], offL[512], wsum4[4];
    __shared__ u32 gbase[MAXNB];
    int t = threadIdx.x;
    for (int i = t; i < 512; i += 256) { cntA[i] = 0; cntB[i] = 0; }
    __syncthreads();
    int T1 = E1 + L1, T = T1 + E2 + L2;
    int base = blockIdx.x * EB2;
    int nE = T - base; if (nE > EB2) nE = EB2;
    for (int j = t; j < nE; j += 256) {
        int s, key;
        edge_at(base + j, src1, dst1, src2, dst2, E1, T1, E2, NR, s, key);
        ldsE[j] = ((u64)(u32)key << 32) | (u32)s;
        atomicAdd(&cntA[key >> 9], 1u);
    }
    __syncthreads();
    scan512f(cntA, offL, wsum4);
    for (int b = t; b < NB; b += 256) {
        u32 c = cntA[b];
        gbase[b] = c ? atomicAdd(&gcur[b], c) : 0u;
    }
    __syncthreads();
    for (int j = t; j < nE; j += 256) {
        u64 e = ldsE[j];
        u32 b = ((u32)(e >> 32)) >> 9;
        u32 r = atomicAdd(&cntB[b], 1u);
        ldsS[offL[b] + r] = e;
    }
    __syncthreads();
    for (int j = t; j < nE; j += 256) {
        u64 e = ldsS[j];
        u32 b = ((u32)(e >> 32)) >> 9;
        pairs[gbase[b] + ((u32)j - offL[b])] = e;
    }
}

// B: per-bucket fine sort -> off[] + sorted[]
__global__ __launch_bounds__(256) void kB(const u64* __restrict__ pairs,
    const u32* __restrict__ bucketBase, int n2,
    int* __restrict__ off, int* __restrict__ sorted)
{
    __shared__ u32 cntA[512], cntB[512], offL[512], wsum4[4];
    __shared__ u32 ldsS[8192];
    int b = blockIdx.x;
    int t = threadIdx.x;
    u32 beg = bucketBase[b], end = bucketBase[b + 1];
    int dstBase = b << 9;
    for (int i = t; i < 512; i += 256) { cntA[i] = 0; cntB[i] = 0; }
    __syncthreads();
    for (u32 j = beg + t; j < end; j += 256) {
        u32 key = (u32)(pairs[j] >> 32);
        atomicAdd(&cntA[key - dstBase], 1u);
    }
    __syncthreads();
    scan512f(cntA, offL, wsum4);
    for (int d = t; d < 512; d += 256) {
        int gk = dstBase + d;
        if (gk < n2) off[gk] = (int)(beg + offL[d]);
    }
    u32 cnt = end - beg;
    bool fast = cnt <= 8192u;
    __syncthreads();
    for (u32 j = beg + t; j < end; j += 256) {
        u64 e = pairs[j];
        u32 d = (u32)(e >> 32) - dstBase;
        u32 r = atomicAdd(&cntB[d], 1u);
        u32 pos = offL[d] + r;
        if (fast) ldsS[pos] = (u32)e;
        else sorted[beg + pos] = (int)(u32)e;
    }
    __syncthreads();
    if (fast) {
        for (u32 j = t; j < cnt; j += 256) sorted[beg + j] = (int)ldsS[j];
    }
}

// ---------------- Fused aggregation: GAT1 (psi) then GAT2 (hs16 gather) -----------
// Phase 2: 32 lanes x 16B cover one 512B row -> 2 edges per wave-step.
__global__ __launch_bounds__(256) void k_agg(const int* __restrict__ off, const int* __restrict__ sorted,
    const float* __restrict__ a_si, const float* __restrict__ psi,
    const float* __restrict__ a_d1, const float* __restrict__ advd,
    const float* __restrict__ cb,
    const float* __restrict__ a_su, const u16* __restrict__ hs16,
    const float* __restrict__ bias, int NR, float* __restrict__ out)
{
    int wave = threadIdx.x >> 6, lane = threadIdx.x & 63;
    int d = blockIdx.x * 4 + wave;
    if (d >= NR) return;
    // ---------- phase 1: GAT1 psi aggregation ----------
    int beg = off[d], end = off[d + 1];
    float ad0 = a_d1[d * 2 + 0], ad1 = a_d1[d * 2 + 1];
    float w0s = 0.f, w1s = 0.f, a00 = 0.f, a01 = 0.f, a10 = 0.f, a11 = 0.f;
    for (int j = beg + lane; j < end; j += 64) {
        int s = sorted[j];
        float2 as = ((const float2*)a_si)[s];
        float e0 = as.x + ad0; e0 = (e0 >= 0.f) ? e0 : 0.2f * e0;
        float e1 = as.y + ad1; e1 = (e1 >= 0.f) ? e1 : 0.2f * e1;
        float x0 = __expf(e0), x1 = __expf(e1);
        float4 p = ((const float4*)psi)[s];
        w0s += x0; w1s += x1;
        a00 += x0 * p.x; a01 += x0 * p.y;
        a10 += x1 * p.z; a11 += x1 * p.w;
    }
    #pragma unroll
    for (int o = 1; o < 64; o <<= 1) {
        w0s += __shfl_xor(w0s, o); w1s += __shfl_xor(w1s, o);
        a00 += __shfl_xor(a00, o); a01 += __shfl_xor(a01, o);
        a10 += __shfl_xor(a10, o); a11 += __shfl_xor(a11, o);
    }
    float inv0g = 1.f / (w0s + 1e-16f), inv1g = 1.f / (w1s + 1e-16f);
    float r0 = advd[d * 2 + 0] + cb[0] + 0.5f * (a00 * inv0g + a10 * inv1g);
    float r1 = advd[d * 2 + 1] + cb[1] + 0.5f * (a01 * inv0g + a11 * inv1g);
    // ---------- phase 2: GAT2 hs16 row gather (2 edges per step) ----------
    int beg2 = off[NR + d], end2 = off[NR + d + 1];
    int g = lane >> 5;                 // edge-parity group (0: even, 1: odd)
    int lg = lane & 31;
    int head = lg >> 4;                // head this lane accumulates
    int hq = lg & 15;                  // 8-channel group within head
    u32 laneoff = (u32)(head * 256 + hq * 16);
    int hsel = head << 5;              // weight source half
    float adh = (lane >= 32) ? r1 : r0;   // batch-phase head = lane>>5
    float wsum = 0.f;
    float acc[8];
    #pragma unroll
    for (int k = 0; k < 8; k++) acc[k] = 0.f;
    const char* hbase = (const char*)hs16;

    for (int base = beg2; base < end2; base += 32) {
        int rem = end2 - base; if (rem > 32) rem = 32;
        int j = lg; if (j >= rem) j = rem - 1;
        int sp = sorted[base + j];
        u32 boff = ((u32)sp) << 9;     // row byte offset (*HC*2)
        float asv = a_su[sp * 2 + g];  // lanes<32: head0 logit; >=32: head1
        float ee = asv + adh; ee = (ee >= 0.f) ? ee : 0.2f * ee;
        float wcomb = __expf(ee);      // weight(edge lg, head lane>>5)
        for (int e = 0; e < rem; e += 2) {
            int eg = e + g;
            bool valid = eg < rem;
            int srcl = valid ? eg : rem - 1;
            u32 bo = __shfl(boff, srcl);
            float W = __shfl(wcomb, hsel + srcl);
            W = valid ? W : 0.f;
            uint4 gg = *(const uint4*)(hbase + (bo + laneoff));
            wsum += W;
            acc[0] += W * bfbits2f(gg.x & 0xFFFFu);
            acc[1] += W * __uint_as_float(gg.x & 0xFFFF0000u);
            acc[2] += W * bfbits2f(gg.y & 0xFFFFu);
            acc[3] += W * __uint_as_float(gg.y & 0xFFFF0000u);
            acc[4] += W * bfbits2f(gg.z & 0xFFFFu);
            acc[5] += W * __uint_as_float(gg.z & 0xFFFF0000u);
            acc[6] += W * bfbits2f(gg.w & 0xFFFFu);
            acc[7] += W * __uint_as_float(gg.w & 0xFFFF0000u);
        }
    }
    // merge edge-parity groups (lane^32: same head/channels, other edge subset)
    wsum += __shfl_xor(wsum, 32);
    #pragma unroll
    for (int k = 0; k < 8; k++) acc[k] += __shfl_xor(acc[k], 32);
    float inv = 1.f / (wsum + 1e-16f);
    #pragma unroll
    for (int k = 0; k < 8; k++) acc[k] *= inv;
    // head mean: lane^16 holds the other head, same channels
    #pragma unroll
    for (int k = 0; k < 8; k++) acc[k] = 0.5f * (acc[k] + __shfl_xor(acc[k], 16));
    if (lane < 16) {
        const float4* b4 = (const float4*)bias;
        float4 bb0 = b4[hq * 2], bb1 = b4[hq * 2 + 1];
        float4 o0, o1;
        o0.x = acc[0] + bb0.x; o0.y = acc[1] + bb0.y;
        o0.z = acc[2] + bb0.z; o0.w = acc[3] + bb0.w;
        o1.x = acc[4] + bb1.x; o1.y = acc[5] + bb1.y;
        o1.z = acc[6] + bb1.z; o1.w = acc[7] + bb1.w;
        float4* op = (float4*)(out + (size_t)d * C + hq * 8);
        op[0] = o0; op[1] = o1;
    }
}

extern "C" void kernel_launch(void* const* d_in, const int* in_sizes, int n_in,
                              void* d_out, int out_size, void* d_ws, size_t ws_size,
                              hipStream_t stream) {
    const int*   user_ids       = (const int*)d_in[0];
    const int*   ingredient_ids = (const int*)d_in[1];
    const float* recipe_x       = (const float*)d_in[2];
    const int*   ing_src        = (const int*)d_in[3];
    const int*   ing_dst        = (const int*)d_in[4];
    const int*   ub_src         = (const int*)d_in[5];
    const int*   ub_dst         = (const int*)d_in[6];
    const float* user_table     = (const float*)d_in[7];
    const float* ing_table      = (const float*)d_in[8];
    const float* W_rl           = (const float*)d_in[9];
    const float* bn_gamma       = (const float*)d_in[11];
    const float* bn_beta        = (const float*)d_in[12];
    const float* g1_ws          = (const float*)d_in[13];
    const float* g1_wd          = (const float*)d_in[14];
    const float* g1_as          = (const float*)d_in[15];
    const float* g1_ad          = (const float*)d_in[16];
    const float* g1_b           = (const float*)d_in[17];
    const float* g2_ws          = (const float*)d_in[18];
    const float* g2_wd          = (const float*)d_in[19];
    const float* g2_as          = (const float*)d_in[20];
    const float* g2_ad          = (const float*)d_in[21];
    const float* g2_b           = (const float*)d_in[22];

    int NU = in_sizes[0];
    int NI = in_sizes[1];
    int NR = in_sizes[2] / DIN;
    int E1 = in_sizes[3];
    int E2 = in_sizes[5];
    int Nmax = (NI > NU) ? NI : NU;
    int L1 = (NI < NR) ? NI : NR;
    int L2 = (NU < NR) ? NU : NR;
    int Etot = E1 + L1 + E2 + L2;
    int n2 = 2 * NR;
    int NB = (n2 + 511) >> 9;

    char* w = (char*)d_ws;
    u16*   hs16  = (u16*)w;    w += (size_t)Nmax * HC * 2;
    float* a_si  = (float*)w;  w += (size_t)NI * 2 * 4;
    float* a_su  = (float*)w;  w += (size_t)NU * 2 * 4;
    float* psi   = (float*)w;  w += (size_t)NI * 4 * 4;
    float* a_d   = (float*)w;  w += (size_t)NR * 2 * 4;
    float* advd  = (float*)w;  w += (size_t)NR * 2 * 4;
    float* stats = (float*)w;  w += 2432 * 4;
    u32*   bucketCnt  = (u32*)w; w += MAXNB * 4;     // adjacent to stats: one memset
    u16*   wsp   = (u16*)w;    w += 32768 * 2;
    u32*   bucketBase = (u32*)w; w += (MAXNB + 1) * 4;
    u32*   gcur  = (u32*)w;    w += MAXNB * 4;
    int*   off   = (int*)w;    w += (size_t)(n2 + 1) * 4;
    int*   sorted= (int*)w;    w += (size_t)Etot * 4;
    w = (char*)(((size_t)w + 15) & ~(size_t)15);
    u64*   pairs = (u64*)w;    w += (size_t)Etot * 8;

    hipMemsetAsync(stats, 0, (2432 + MAXNB) * 4, stream);

    int SB = (NR + 255) / 256;
    int AB = (Etot + EB1 - 1) / EB1;
    k_init<<<SB + AB, 256, 0, stream>>>(recipe_x, NR, stats, SB,
                                        ing_src, ing_dst, ub_src, ub_dst,
                                        E1, L1, E2, L2, NB, bucketCnt);
    k_precomp_pack<<<34, 256, 0, stream>>>(stats, W_rl, bn_gamma, bn_beta,
                                           g1_wd, g1_ad, g2_wd, g2_ad,
                                           g1_ws, g1_as, g2_ws, g2_as, g1_b,
                                           1.0f / NR, wsp,
                                           bucketCnt, NB, n2, bucketBase, gcur, off);
    kA2<<<(Etot + EB2 - 1) / EB2, 256, 0, stream>>>(ing_src, ing_dst, ub_src, ub_dst,
                                                    E1, L1, E2, L2, NR, NB, gcur, pairs);
    int R0B = (NR + 255) / 256;
    int IB  = (NI + 31) / 32;
    int HB  = (NU + 31) / 32;
    k_feat<<<R0B + IB + HB, 256, 0, stream>>>(recipe_x, NR, R0B, IB,
                                              ing_table, ingredient_ids, NI,
                                              user_table, user_ids, NU,
                                              wsp, stats, a_d, advd, a_si, psi,
                                              hs16, a_su);
    kB<<<NB, 256, 0, stream>>>(pairs, bucketBase, n2, off, sorted);
    // fused GAT1 + GAT2 aggregation
    k_agg<<<(NR + 3) / 4, 256, 0, stream>>>(off, sorted, a_si, psi, a_d, advd,
                                            stats + 1188, a_su, hs16, g2_b, NR,
                                            (float*)d_out);
}